// Round 7
// baseline (177.056 us; speedup 1.0000x reference)
//
#include <hip/hip_runtime.h>

// HMM forward, log space. B=64 chains, D=128 steps, A=128 states.
// v_{t+1}[j] = log(sum_k exp(v_t[k]-M) * E[t][k->j]) + M + BC[b][t][j]
// E fp16 pair-packed; layout [t][q][j] so loads are 1KB contiguous per instr.
// fwd: 64 blocks x 2 waves; lane owns j = 64*w + lane (full k-dot per lane,
// no cross-half combine). LAGGED GLOBAL NORMALIZER: publish exp(v - M_prev);
// BC<=0 bounds ew <= 128 (fp16-safe); max-reduction runs off critical path.
// Raw s_barrier (lgkmcnt only) keeps global prefetch in flight.

#define B_ 64
#define D_ 128
#define A_ 128
#define T_ 127

// ws layout (4-byte units), ~8.33 MB
#define E16_UINTS (T_ * 8192)      // uint(t,q,j,c) at t*8192+q*512+j*4+c
#define BC_OFF E16_UINTS           // [b][t][j] fp32
#define BC_SZ (B_ * T_ * A_)
#define LP_OFF (BC_OFF + BC_SZ)    // log_p_a1[j] fp32

typedef _Float16 h2 __attribute__((ext_vector_type(2)));

__device__ __forceinline__ float dot2acc(unsigned int e, unsigned int s, float acc) {
    return __builtin_amdgcn_fdot2(__builtin_bit_cast(h2, e),
                                  __builtin_bit_cast(h2, s), acc, false);
}
__device__ __forceinline__ int packrtz(float a, float b) {
    auto p = __builtin_amdgcn_cvt_pkrtz(a, b);
    return __builtin_bit_cast(int, p);
}

template <int CTRL>
__device__ __forceinline__ float dpp_mov_self(float x) {
    return __int_as_float(__builtin_amdgcn_update_dpp(
        __float_as_int(x), __float_as_int(x), CTRL, 0xF, 0xF, false));
}
template <int CTRL>
__device__ __forceinline__ float dpp_mov_zero(float x) {
    return __int_as_float(__builtin_amdgcn_update_dpp(
        0, __float_as_int(x), CTRL, 0xF, 0xF, true));
}
// after this chain, lane 63 holds the full-wave max (no readlane)
__device__ __forceinline__ float wave_max_partial(float x) {
    x = fmaxf(x, dpp_mov_self<0x111>(x));
    x = fmaxf(x, dpp_mov_self<0x112>(x));
    x = fmaxf(x, dpp_mov_self<0x114>(x));
    x = fmaxf(x, dpp_mov_self<0x118>(x));
    x = fmaxf(x, dpp_mov_self<0x142>(x));
    x = fmaxf(x, dpp_mov_self<0x143>(x));
    return x;
}
__device__ __forceinline__ float wave_max_bcast(float x) {
    return __int_as_float(__builtin_amdgcn_readlane(
        __float_as_int(wave_max_partial(x)), 63));
}
__device__ __forceinline__ float wave_sum_bcast(float x) {
    x += dpp_mov_zero<0x111>(x);
    x += dpp_mov_zero<0x112>(x);
    x += dpp_mov_zero<0x114>(x);
    x += dpp_mov_zero<0x118>(x);
    x += dpp_mov_zero<0x142>(x);
    x += dpp_mov_zero<0x143>(x);
    return __int_as_float(__builtin_amdgcn_readlane(__float_as_int(x), 63));
}

// ---------------- merged prep: 127 blocks x 256, LDS-staged coalesced ----------------
__global__ __launch_bounds__(256) void prep(const float* __restrict__ uT,
                                            const float* __restrict__ u1,
                                            const float* __restrict__ x,
                                            const float* __restrict__ lg,
                                            float* __restrict__ ws,
                                            float* __restrict__ out) {
    __shared__ float ul[128 * 128];   // exactly 64KB
    const int t = blockIdx.x, tid = threadIdx.x;
    const float* u = uT + (size_t)t * A_ * A_;

    // stage 64KB coalesced (float4)
    for (int i = tid; i < 4096; i += 256) {
        float4 v4 = ((const float4*)u)[i];
        *(float4*)&ul[(i >> 5) * 128 + (i & 31) * 4] = v4;
    }
    __syncthreads();

    // thread r<128: Z[r] = lse_j ul[r][j]; then in-place ul[r][j] -= Z[r]
    // rotated j index -> conflict-free banks
    if (tid < 128) {
        const int r = tid;
        float mx = -1e30f;
        for (int it = 0; it < 128; it++) mx = fmaxf(mx, ul[r * 128 + ((it + r) & 127)]);
        float s = 0.f;
        for (int it = 0; it < 128; it++) s += __expf(ul[r * 128 + ((it + r) & 127)] - mx);
        float Z = mx + __logf(s);
        for (int it = 0; it < 128; it++) ul[r * 128 + ((it + r) & 127)] -= Z;
    }
    __syncthreads();

    // E16: uint(t,q,j,c) = pack(e(2i,j), e(2i+1,j)), i = 4q+c
    unsigned int* Et = (unsigned int*)ws + (size_t)t * 8192;
    for (int it = 0; it < 32; it++) {
        int a = it * 256 + tid;           // 0..8191
        int c = a & 3, j = (a >> 2) & 127, q = a >> 9;
        int i = 4 * q + c;
        float e0 = __expf(ul[(2 * i) * 128 + j]);
        float e1 = __expf(ul[(2 * i + 1) * 128 + j]);
        Et[a] = (unsigned int)packrtz(e0, e1);
    }

    // BC[b][t][j] = bern(x[b][t+1], j)  (plain layout)
    {
        int j = tid & 127, hb = tid >> 7;
        float lv = lg[(t + 1) * A_ + j];
        float sp = (lv > 0.f) ? (lv + log1pf(__expf(-lv))) : log1pf(__expf(lv));
        float g0 = -sp, g1 = lv - sp;
        float* BC = ws + BC_OFF;
        for (int b = hb * 32; b < hb * 32 + 32; b++) {
            float xv = x[b * D_ + t + 1];
            BC[((size_t)b * T_ + t) * A_ + j] = (xv != 0.f) ? g1 : g0;
        }
    }

    // block 0 wave 0: log_softmax(u1) -> LP + output 1
    if (t == 0 && tid < 64) {
        int lane = tid;
        float a = u1[lane], c = u1[lane + 64];
        float mx = wave_max_bcast(fmaxf(a, c));
        float s = wave_sum_bcast(__expf(a - mx) + __expf(c - mx));
        float lse = mx + __logf(s);
        ws[LP_OFF + lane] = a - lse;
        ws[LP_OFF + lane + 64] = c - lse;
        out[B_ * A_ + lane] = a - lse;
        out[B_ * A_ + lane + 64] = c - lse;
    }
}

// ---------------- main: 64 blocks x 128 (2 waves), lagged normalizer ----------------
#define BARRIER() asm volatile("s_waitcnt lgkmcnt(0)\n\ts_barrier" ::: "memory")

#define STEP(T, EC, EP, BCC, BCP, DOPF)                                       \
    {                                                                         \
        const int p = (T) & 1, np = p ^ 1;                                    \
        if (DOPF) { /* prefetch step T+1 */                                   \
            const uint4* pfp = (const uint4*)(Eb + (size_t)((T) + 1) * 32768);\
            _Pragma("unroll") for (int q = 0; q < 16; q++) EP[q] = pfp[q*128];\
            BCP = BCg[((T) + 1) * A_];                                        \
            __builtin_amdgcn_sched_barrier(0);                                \
        }                                                                     \
        float2 vm2 = *(const float2*)&vml[p][0];                              \
        float Mcur = fmaxf(vm2.x, vm2.y);                                     \
        const uint4* ewp = (const uint4*)&ewl[p][0];                          \
        float a0 = 0, a1 = 0, a2 = 0, a3 = 0;                                 \
        _Pragma("unroll") for (int q = 0; q < 16; q++) {                      \
            uint4 e = ewp[q];                                                 \
            a0 = dot2acc(EC[q].x, e.x, a0);                                   \
            a1 = dot2acc(EC[q].y, e.y, a1);                                   \
            a2 = dot2acc(EC[q].z, e.z, a2);                                   \
            a3 = dot2acc(EC[q].w, e.w, a3);                                   \
        }                                                                     \
        float S = (a0 + a1) + (a2 + a3);                                      \
        float vnew = __logf(S) + Mp + BCC;                                    \
        ewl[np][j] = (_Float16)__expf(vnew - Mcur);   /* ew <= 128, fp16 ok */\
        float wm = wave_max_partial(vnew);            /* off critical path */ \
        if (lane == 63) vml[np][w] = wm;                                      \
        v = vnew;                                                             \
        Mp = Mcur;                                                            \
        BARRIER();                                                            \
    }

__global__ __launch_bounds__(128) void fwd(const float* __restrict__ x,
                                           const float* __restrict__ lg,
                                           const float* __restrict__ ws,
                                           float* __restrict__ out) {
    __shared__ __align__(16) _Float16 ewl[2][A_];
    __shared__ float vml[2][2];
    __shared__ float sums[2];
    const int b = blockIdx.x, tid = threadIdx.x;
    const int w = tid >> 6, lane = tid & 63;
    const int j = 64 * w + lane;

    const char* Eb = (const char*)ws + j * 16;     // + t*32768 + q*2048
    const float* BCg = ws + BC_OFF + (size_t)b * T_ * A_ + j;
    const float* LP = ws + LP_OFF;

    // init: v_0[j] = log_p_a1[j] + bern(x[b][0], j)
    float ll = lg[j];
    float sp = (ll > 0.f) ? (ll + log1pf(__expf(-ll))) : log1pf(__expf(ll));
    float xv0 = x[b * D_];
    float v = LP[j] + ((xv0 != 0.f) ? (ll - sp) : (-sp));
    float wm0 = wave_max_bcast(v);
    if (lane == 0) vml[0][w] = wm0;
    BARRIER();
    float Mp = fmaxf(vml[0][0], vml[0][1]);        // M_0 (global)
    ewl[0][j] = (_Float16)__expf(v - Mp);          // <= 1

    uint4 E0[16], E1[16];
    float bc0, bc1;
    {
        const uint4* p0 = (const uint4*)(Eb);
#pragma unroll
        for (int q = 0; q < 16; q++) E0[q] = p0[q * 128];
        bc0 = BCg[0];
        __builtin_amdgcn_sched_barrier(0);
    }
    bc1 = 0.f;
    BARRIER();

    for (int t = 0; t < 126; t += 2) {   // steps 0..125, prefetch 1..126
        STEP(t + 0, E0, E1, bc0, bc1, 1)
        STEP(t + 1, E1, E0, bc1, bc0, 1)
    }
    STEP(126, E0, E1, bc0, bc1, 0)

    // final: L = lse_j v_127[j]; vml[1] holds wave maxes of v_127
    float Mf = fmaxf(vml[1][0], vml[1][1]);
    float sw = wave_sum_bcast(__expf(v - Mf));
    if (lane == 0) sums[w] = sw;
    BARRIER();
    float L = Mf + __logf(sums[0] + sums[1]);
    out[b * A_ + j] = L;
}

extern "C" void kernel_launch(void* const* d_in, const int* in_sizes, int n_in,
                              void* d_out, int out_size, void* d_ws, size_t ws_size,
                              hipStream_t stream) {
    const float* x = (const float*)d_in[0];    // [B,D]
    const float* u1 = (const float*)d_in[1];   // [1,1,1,A]
    const float* uT = (const float*)d_in[2];   // [D-1,A,A]
    const float* lg = (const float*)d_in[3];   // [1,D,1,A]
    float* ws = (float*)d_ws;                  // ~8.33 MB
    float* out = (float*)d_out;

    prep<<<dim3(T_), dim3(256), 0, stream>>>(uT, u1, x, lg, ws, out);
    fwd<<<dim3(B_), dim3(128), 0, stream>>>(x, lg, ws, out);
}